// Round 1
// baseline (302248.438 us; speedup 1.0000x reference)
//
#include <hip/hip_runtime.h>
#include <math.h>

#define GROUPS   8
#define HIDDEN   2048
#define TSTEPS   4096
#define RADIUS_F 100.0f
#define BPG      32                 // blocks per group
#define NBLOCKS  (GROUPS * BPG)     // 256
#define BLOCK    512                // 8 waves
#define ROWS_PB  64                 // rows per block  (HIDDEN / BPG)
#define ROWS_PW  8                  // rows per wave   (ROWS_PB / 8 waves)

// Persistent cooperative kernel: whole T=4096 scan in one launch.
// Each block: 64 rows of one group's matvec; h[g] replicated in LDS.
// One device-scope barrier per step (monotonic counter), double-buffered pre.
__global__ __launch_bounds__(BLOCK, 2) void esn_persistent(
    const float* __restrict__ x,      // [T]
    const float* __restrict__ W_ih,   // [H]
    const float* __restrict__ W_hh,   // [G,H,H]
    float* __restrict__ out,          // [T, G*H]
    float* __restrict__ preBuf,       // 2 * G*H floats (double buffer)
    unsigned* __restrict__ ctr)       // G counters, zeroed before launch
{
    const int tid  = threadIdx.x;
    const int wave = tid >> 6;
    const int lane = tid & 63;
    const int g    = blockIdx.x & (GROUPS - 1);   // blockIdx%8 -> XCD affinity
    const int sub  = blockIdx.x >> 3;             // 0..31 within group
    const int rowBase = sub * ROWS_PB;

    __shared__ float h_lds[HIDDEN];          // replicated group state
    __shared__ float wih_lds[ROWS_PB];
    __shared__ float red[BLOCK / 64];
    __shared__ float scale_sh;

    ((float4*)h_lds)[tid] = make_float4(0.f, 0.f, 0.f, 0.f);   // 512*4 = 2048
    if (tid < ROWS_PB / 4)
        ((float4*)wih_lds)[tid] = ((const float4*)(W_ih + rowBase))[tid];
    __syncthreads();

    const float lr  = (float)(GROUPS - g) / (float)GROUPS;  // LEAKY=1
    const float olr = 1.0f - lr;
    const float lrR = lr * RADIUS_F;

    const float* Wg = W_hh + ((size_t)g * HIDDEN + rowBase) * (size_t)HIDDEN;

    for (int t = 0; t < TSTEPS; ++t) {
        const int buf = t & 1;
        float* pb = preBuf + (size_t)buf * (GROUPS * HIDDEN) + g * HIDDEN;
        const float xt = x[t];

        // ---- phase 1: pre rows for our 64 rows ----
        // lane l owns cols {4l + 256k}, k=0..7 ; preload h slice to regs
        float4 hreg[8];
        #pragma unroll
        for (int k = 0; k < 8; ++k)
            hreg[k] = *(const float4*)&h_lds[4 * lane + 256 * k];

        #pragma unroll
        for (int r = 0; r < ROWS_PW; ++r) {
            const int row = wave * ROWS_PW + r;               // 0..63 local
            const float4* wrow = (const float4*)(Wg + (size_t)row * HIDDEN);
            float acc = 0.f;
            #pragma unroll
            for (int k = 0; k < 8; ++k) {
                const float4 wv = wrow[lane + 64 * k];        // coalesced 1KB/wave
                acc = fmaf(wv.x, hreg[k].x, acc);
                acc = fmaf(wv.y, hreg[k].y, acc);
                acc = fmaf(wv.z, hreg[k].z, acc);
                acc = fmaf(wv.w, hreg[k].w, acc);
            }
            #pragma unroll
            for (int off = 32; off; off >>= 1)
                acc += __shfl_xor(acc, off, 64);
            if (lane == 0)
                pb[rowBase + row] = fmaf(xt, wih_lds[row], acc);
        }

        // ---- per-group device-scope barrier (one per step) ----
        __threadfence();            // agent-release of pre stores (all threads)
        __syncthreads();
        if (tid == 0) {
            __hip_atomic_fetch_add(&ctr[g], 1u, __ATOMIC_RELEASE, __HIP_MEMORY_SCOPE_AGENT);
            const unsigned tgt = (unsigned)(BPG * (t + 1));   // monotonic target
            while (__hip_atomic_load(&ctr[g], __ATOMIC_RELAXED, __HIP_MEMORY_SCOPE_AGENT) < tgt)
                __builtin_amdgcn_s_sleep(1);
        }
        __syncthreads();
        __threadfence();            // agent-acquire before reading peers' pre

        // ---- phase 3: full pre read, norm, h update (replicated, bit-identical) ----
        const float* pg = preBuf + (size_t)buf * (GROUPS * HIDDEN) + g * HIDDEN;
        const float4 p4 = *(const float4*)&pg[tid * 4];
        float ss = p4.x * p4.x + p4.y * p4.y + p4.z * p4.z + p4.w * p4.w;
        #pragma unroll
        for (int off = 32; off; off >>= 1)
            ss += __shfl_xor(ss, off, 64);
        if (lane == 0) red[wave] = ss;
        __syncthreads();
        if (tid == 0) {
            float s = 0.f;
            #pragma unroll
            for (int w = 0; w < BLOCK / 64; ++w) s += red[w];
            scale_sh = lrR / sqrtf(s);
        }
        __syncthreads();
        const float sc = scale_sh;
        const float4 h4 = *(const float4*)&h_lds[tid * 4];
        float4 hn;
        hn.x = olr * h4.x + sc * p4.x;
        hn.y = olr * h4.y + sc * p4.y;
        hn.z = olr * h4.z + sc * p4.z;
        hn.w = olr * h4.w + sc * p4.w;
        *(float4*)&h_lds[tid * 4] = hn;
        __syncthreads();
        // write out for our own 64 cols only (avoid 32x duplicate writes)
        if (tid < ROWS_PB / 4) {
            const float4 o = *(const float4*)&h_lds[rowBase + tid * 4];
            *(float4*)&out[(size_t)t * (GROUPS * HIDDEN) + g * HIDDEN + rowBase + tid * 4] = o;
        }
    }
}

extern "C" void kernel_launch(void* const* d_in, const int* in_sizes, int n_in,
                              void* d_out, int out_size, void* d_ws, size_t ws_size,
                              hipStream_t stream) {
    const float* x   = (const float*)d_in[0];   // [4096]
    const float* Wih = (const float*)d_in[1];   // [2048]
    const float* Whh = (const float*)d_in[2];   // [8*2048*2048]
    float* out = (float*)d_out;

    unsigned* ctr  = (unsigned*)d_ws;                       // 8 counters
    float* preBuf  = (float*)((char*)d_ws + 256);           // 2 * 64KB

    // d_ws is re-poisoned to 0xAA before every timed launch: zero counters.
    hipMemsetAsync(d_ws, 0, 256, stream);

    void* args[] = { (void*)&x, (void*)&Wih, (void*)&Whh,
                     (void*)&out, (void*)&preBuf, (void*)&ctr };
    hipLaunchCooperativeKernel((const void*)esn_persistent,
                               dim3(NBLOCKS), dim3(BLOCK), args, 0, stream);
}

// Round 3
// 35344.971 us; speedup vs baseline: 8.5514x; 8.5514x over previous
//
#include <hip/hip_runtime.h>
#include <math.h>

#define GROUPS   8
#define HIDDEN   2048
#define TSTEPS   4096
#define RADIUS_F 100.0f
#define BPG      32                 // blocks per group
#define NBLOCKS  (GROUPS * BPG)     // 256
#define BLOCK    512                // 8 waves
#define ROWS_PB  64                 // rows per block
#define ROWS_PW  8                  // rows per wave
#define GH       (GROUPS * HIDDEN)

typedef float vfloat4 __attribute__((ext_vector_type(4)));  // clang-native, builtin-friendly

// Persistent cooperative kernel, one device barrier per step.
// R2/R3 changes vs R1:
//  - per-group counter on its OWN 256B line + s_sleep(4) poll backoff
//  - NO __threadfence anywhere: pre exchanged via agent-scope relaxed
//    atomics; counter add is RELEASE. Weights stay plain cached loads;
//    L2 never invalidated.
//  - phase 1 accumulates 8 row-dots before any shuffle -> 64 independent
//    weight loads per wave for MLP.
//  - out written nontemporal (never re-read; keeps L2 clean).
__global__ __launch_bounds__(BLOCK, 2) void esn_persistent(
    const float* __restrict__ x,      // [T]
    const float* __restrict__ W_ih,   // [H]
    const float* __restrict__ W_hh,   // [G,H,H]
    float* __restrict__ out,          // [T, G*H]
    float* preBuf,                    // 2 * G*H floats (double buffer)
    unsigned* ctr)                    // counters, 64-uint stride per group
{
    const int tid  = threadIdx.x;
    const int wave = tid >> 6;
    const int lane = tid & 63;
    const int g    = blockIdx.x & (GROUPS - 1);   // XCD affinity
    const int sub  = blockIdx.x >> 3;             // 0..31 within group
    const int rowBase = sub * ROWS_PB;

    __shared__ float h_lds[HIDDEN];
    __shared__ float wih_lds[ROWS_PB];
    __shared__ float red[BLOCK / 64];

    ((float4*)h_lds)[tid] = make_float4(0.f, 0.f, 0.f, 0.f);
    if (tid < ROWS_PB / 4)
        ((float4*)wih_lds)[tid] = ((const float4*)(W_ih + rowBase))[tid];
    __syncthreads();

    const float lr  = (float)(GROUPS - g) / (float)GROUPS;
    const float olr = 1.0f - lr;
    const float lrR = lr * RADIUS_F;

    const float* Wg = W_hh + ((size_t)g * HIDDEN + rowBase) * (size_t)HIDDEN;
    unsigned* myctr = ctr + g * 64;               // 256B apart per group

    for (int t = 0; t < TSTEPS; ++t) {
        const int buf = t & 1;
        float* pb = preBuf + (size_t)buf * GH + g * HIDDEN;
        const float xt = x[t];

        // ---- phase 1: 8 row-dots per wave, loads first, reduce after ----
        float acc[ROWS_PW] = {0.f, 0.f, 0.f, 0.f, 0.f, 0.f, 0.f, 0.f};
        #pragma unroll
        for (int k = 0; k < 8; ++k) {
            const float4 hv = *(const float4*)&h_lds[4 * lane + 256 * k];
            #pragma unroll
            for (int r = 0; r < ROWS_PW; ++r) {
                const float4 wv =
                    ((const float4*)(Wg + (size_t)(wave * ROWS_PW + r) * HIDDEN))[lane + 64 * k];
                acc[r] = fmaf(wv.x, hv.x, acc[r]);
                acc[r] = fmaf(wv.y, hv.y, acc[r]);
                acc[r] = fmaf(wv.z, hv.z, acc[r]);
                acc[r] = fmaf(wv.w, hv.w, acc[r]);
            }
        }
        #pragma unroll
        for (int r = 0; r < ROWS_PW; ++r) {
            float a = acc[r];
            #pragma unroll
            for (int off = 32; off; off >>= 1)
                a += __shfl_xor(a, off, 64);
            acc[r] = a;
        }
        // lane r (r<8) publishes row wave*8+r  (static-index select chain)
        float myv = acc[0];
        #pragma unroll
        for (int r = 1; r < ROWS_PW; ++r)
            if (lane == r) myv = acc[r];
        if (lane < ROWS_PW) {
            const int rowL = wave * ROWS_PW + lane;
            const float pre = fmaf(xt, wih_lds[rowL], myv);
            __hip_atomic_store(&pb[rowBase + rowL], pre,
                               __ATOMIC_RELAXED, __HIP_MEMORY_SCOPE_AGENT);
        }

        // ---- per-group device barrier (counter on private line) ----
        __syncthreads();   // drains vmcnt -> pre stores visible at coherence point
        if (tid == 0) {
            __hip_atomic_fetch_add(myctr, 1u, __ATOMIC_RELEASE, __HIP_MEMORY_SCOPE_AGENT);
            const unsigned tgt = (unsigned)(BPG * (t + 1));   // monotonic
            while (__hip_atomic_load(myctr, __ATOMIC_RELAXED, __HIP_MEMORY_SCOPE_AGENT) < tgt)
                __builtin_amdgcn_s_sleep(4);
        }
        __syncthreads();

        // ---- phase 3: read full pre (agent-scope), norm, h update ----
        float* pg = preBuf + (size_t)buf * GH + g * HIDDEN;
        const float p0 = __hip_atomic_load(&pg[tid * 4 + 0], __ATOMIC_RELAXED, __HIP_MEMORY_SCOPE_AGENT);
        const float p1 = __hip_atomic_load(&pg[tid * 4 + 1], __ATOMIC_RELAXED, __HIP_MEMORY_SCOPE_AGENT);
        const float p2 = __hip_atomic_load(&pg[tid * 4 + 2], __ATOMIC_RELAXED, __HIP_MEMORY_SCOPE_AGENT);
        const float p3 = __hip_atomic_load(&pg[tid * 4 + 3], __ATOMIC_RELAXED, __HIP_MEMORY_SCOPE_AGENT);

        float ss = p0 * p0 + p1 * p1 + p2 * p2 + p3 * p3;
        #pragma unroll
        for (int off = 32; off; off >>= 1)
            ss += __shfl_xor(ss, off, 64);
        if (lane == 0) red[wave] = ss;
        __syncthreads();
        float s = 0.f;
        #pragma unroll
        for (int w = 0; w < BLOCK / 64; ++w) s += red[w];
        const float sc = lrR / sqrtf(s);          // identical in every block

        const float4 h4 = *(const float4*)&h_lds[tid * 4];
        float4 hn;
        hn.x = olr * h4.x + sc * p0;
        hn.y = olr * h4.y + sc * p1;
        hn.z = olr * h4.z + sc * p2;
        hn.w = olr * h4.w + sc * p3;
        *(float4*)&h_lds[tid * 4] = hn;

        // our own 64 cols -> out, straight from registers, nontemporal
        if (tid >= rowBase / 4 && tid < rowBase / 4 + ROWS_PB / 4) {
            vfloat4 hv4;
            hv4.x = hn.x; hv4.y = hn.y; hv4.z = hn.z; hv4.w = hn.w;
            vfloat4* op = (vfloat4*)&out[(size_t)t * GH + g * HIDDEN + tid * 4];
            __builtin_nontemporal_store(hv4, op);
        }
        __syncthreads();   // h_lds ready for next step
    }
}

extern "C" void kernel_launch(void* const* d_in, const int* in_sizes, int n_in,
                              void* d_out, int out_size, void* d_ws, size_t ws_size,
                              hipStream_t stream) {
    const float* x   = (const float*)d_in[0];   // [4096]
    const float* Wih = (const float*)d_in[1];   // [2048]
    const float* Whh = (const float*)d_in[2];   // [8*2048*2048]
    float* out = (float*)d_out;

    unsigned* ctr  = (unsigned*)d_ws;                       // 8 counters, 256B stride
    float* preBuf  = (float*)((char*)d_ws + 4096);          // 2 * 64KB

    (void)hipMemsetAsync(d_ws, 0, 4096, stream);            // zero counters (ws re-poisoned)

    void* args[] = { (void*)&x, (void*)&Wih, (void*)&Whh,
                     (void*)&out, (void*)&preBuf, (void*)&ctr };
    (void)hipLaunchCooperativeKernel((const void*)esn_persistent,
                                     dim3(NBLOCKS), dim3(BLOCK), args, 0, stream);
}